// Round 2
// baseline (113073.083 us; speedup 1.0000x reference)
//
#include <hip/hip_runtime.h>
#include <hip/hip_bf16.h>

// bigRSNN: T=8192 strictly-serial spiking RNN.
// Phase 1: 64 blocks x 512 threads = 512 fully independent waves (NO barriers,
// NO LDS in the step loop). Wave w of block b owns neuron rows 2g,2g+1
// (g = b*8+w is implicit: rows blk*16 + 2w + half). Spike exchange: one
// tag-counted u32 per (t, block) in ws — bits 0..15 = spike bits, bits 16+ =
// completion count accumulated by 8 per-wave relaxed agent atomic_adds.
// Consumers poll until count==8. Data and flag share the word -> relaxed is
// safe. Phase 2: readout GEMM over the raster + 10 IIR scans + head mean.

constexpr int T_STEPS = 8192;
constexpr int IN_DIM  = 192;
constexpr int H_DIM   = 1024;
constexpr int NBLK    = 64;

// ---------------------------------------------------------------- clear ws
__global__ void k_clear(unsigned int* __restrict__ p, int n) {
    int i = blockIdx.x * blockDim.x + threadIdx.x;
    if (i < n) p[i] = 0u;
}

// ---------------------------------------------------------------- phase 1
__global__ __launch_bounds__(512, 1) void k_phase1(
    const float* __restrict__ x,       // [T][192]
    const float* __restrict__ W_in,    // [H][192]
    const float* __restrict__ V,       // [H][H]
    const float* __restrict__ b_rec,   // [H]
    const float* __restrict__ alpha_h_p,
    const float* __restrict__ beta_h_p,
    unsigned int* __restrict__ spkWords) // [T][64]
{
    const int tid  = threadIdx.x;
    const int blk  = blockIdx.x;       // 0..63
    const int w    = tid >> 6;         // wave 0..7
    const int l    = tid & 63;         // lane
    const int half = l >> 5;           // 0/1 -> which of the wave's 2 rows
    const int cg   = l & 31;           // column group: cols cg*32..cg*32+31
    const int row  = (blk << 4) + (w << 1) + half;

    // V fragment: 32 consecutive columns in VGPRs
    float4 vfrag[8];
    {
        const float4* vp = (const float4*)(V + (size_t)row * H_DIM + cg * 32);
        #pragma unroll
        for (int i = 0; i < 8; ++i) vfrag[i] = vp[i];
    }
    // W_in fragment: k = cg*6 .. cg*6+5
    float wfrag[6];
    {
        const float* wp = W_in + row * IN_DIM + cg * 6;
        #pragma unroll
        for (int i = 0; i < 6; ++i) wfrag[i] = wp[i];
    }
    const float b_r = b_rec[row];
    const float ah  = alpha_h_p[0];
    const float bh  = beta_h_p[0];

    const float* xptr = x + cg * 6;    // x[t] row, advanced by IN_DIM per step
    float xr[6], xf[6];
    #pragma unroll
    for (int i = 0; i < 6; ++i) xr[i] = 0.0f;   // x[-1] = 0

    float syn = 0.f, mem = 0.f, prev = 0.f;     // replicated across 32 lanes
    unsigned int vv = 0u;                        // polled word set for t-1

    for (int t = 0; t < T_STEPS; ++t) {
        // prefetch x[t] (consumed next iteration); overlaps everything below
        #pragma unroll
        for (int i = 0; i < 6; ++i) xf[i] = xptr[i];

        // my two 16-bit spike words for cols cg*32..+31 (from own wave's poll)
        unsigned int b0 = __shfl(vv, cg * 2,     64) & 0xffffu;
        unsigned int b1 = __shfl(vv, cg * 2 + 1, 64) & 0xffffu;

        // V @ S_{t-1} over my 32 columns (two parallel FMA chains)
        float a0 = 0.f, a1 = 0.f;
        #pragma unroll
        for (int i = 0; i < 4; ++i) {
            a0 = fmaf((float)((b0 >> (4 * i + 0)) & 1u), vfrag[i].x, a0);
            a0 = fmaf((float)((b0 >> (4 * i + 1)) & 1u), vfrag[i].y, a0);
            a0 = fmaf((float)((b0 >> (4 * i + 2)) & 1u), vfrag[i].z, a0);
            a0 = fmaf((float)((b0 >> (4 * i + 3)) & 1u), vfrag[i].w, a0);
            a1 = fmaf((float)((b1 >> (4 * i + 0)) & 1u), vfrag[4 + i].x, a1);
            a1 = fmaf((float)((b1 >> (4 * i + 1)) & 1u), vfrag[4 + i].y, a1);
            a1 = fmaf((float)((b1 >> (4 * i + 2)) & 1u), vfrag[4 + i].z, a1);
            a1 = fmaf((float)((b1 >> (4 * i + 3)) & 1u), vfrag[4 + i].w, a1);
        }
        // + W_in @ x[t-1] over my 6 k's
        #pragma unroll
        for (int i = 0; i < 6; ++i) a1 = fmaf(wfrag[i], xr[i], a1);
        float acc = a0 + a1;

        // reduce across the 32 lanes of this row (xor stays in-half)
        #pragma unroll
        for (int m = 1; m < 32; m <<= 1) acc += __shfl_xor(acc, m, 64);

        // state update (identical in all 32 lanes of the row)
        float cur = acc + b_r;
        syn = fmaf(ah, syn, cur);
        mem = fmaf(bh, mem, syn) * (1.0f - prev);  // zero-reset, previous spike
        float spk = (mem > 1.0f) ? 1.0f : 0.0f;
        prev = spk;

        // publish: wave-wide ballot -> one atomic_add carrying 2 bits + count
        unsigned long long bal = __ballot(spk > 0.5f);
        if (l == 0) {
            unsigned int add = ((unsigned int)(bal & 1ull)         << (2 * w))
                             | ((unsigned int)((bal >> 32) & 1ull) << (2 * w + 1))
                             | 0x10000u;
            (void)__hip_atomic_fetch_add(&spkWords[(size_t)t * 64 + blk], add,
                                         __ATOMIC_RELAXED, __HIP_MEMORY_SCOPE_AGENT);
        }

        // poll step-t words for the next iteration (lane l <-> word l)
        if (t + 1 < T_STEPS) {
            const unsigned int* pw = &spkWords[(size_t)t * 64 + l];
            unsigned int nv = __hip_atomic_load(pw, __ATOMIC_RELAXED,
                                                __HIP_MEMORY_SCOPE_AGENT);
            while (__any((nv >> 16) != 8u)) {
                if ((nv >> 16) != 8u)
                    nv = __hip_atomic_load(pw, __ATOMIC_RELAXED,
                                           __HIP_MEMORY_SCOPE_AGENT);
            }
            vv = nv;
        }

        #pragma unroll
        for (int i = 0; i < 6; ++i) xr[i] = xf[i];
        xptr += IN_DIM;
    }
}

// ---------------------------------------------------------------- phase 2A
// R[t][row] = W_out[row] . S_{t-1}  (row = h*2+o, 10 rows). W_out staged in
// LDS with pad (stride 1033) to break row-bank conflicts.
__global__ __launch_bounds__(256, 1) void k_readout_mm(
    const unsigned int* __restrict__ spkWords,
    const float* __restrict__ W_out,   // [10][1024]
    float* __restrict__ R)             // [T][10]
{
    __shared__ float wlds[10 * 1033];
    for (int i = threadIdx.x; i < 10 * 1024; i += 256) {
        int r = i >> 10, c = i & 1023;
        wlds[r * 1033 + c] = W_out[i];
    }
    __syncthreads();

    int tid = threadIdx.x;
    if (tid >= 250) return;
    int tl = tid / 10, rowr = tid - tl * 10;
    int t = blockIdx.x * 25 + tl;
    if (t >= T_STEPS) return;

    float acc = 0.f;
    if (t > 0) {
        const unsigned int* wp = spkWords + (size_t)(t - 1) * 64;
        const float* wr = &wlds[rowr * 1033];
        for (int ww = 0; ww < 64; ++ww) {
            unsigned int bits = wp[ww] & 0xffffu;
            const float* wb = wr + ww * 16;
            #pragma unroll
            for (int j = 0; j < 16; ++j)
                acc = fmaf((float)((bits >> j) & 1u), wb[j], acc);
        }
    }
    R[t * 10 + rowr] = acc;
}

// ---------------------------------------------------------------- phase 2B
__global__ void k_scan(const float* __restrict__ R,
                       const float* __restrict__ alpha_r,
                       const float* __restrict__ beta_r,
                       float* __restrict__ memr_all)   // [T][10]
{
    int lane = threadIdx.x;
    bool act = lane < 10;
    float a = act ? alpha_r[lane >> 1] : 0.f;
    float b = act ? beta_r[lane >> 1] : 0.f;
    float syn = 0.f, mem = 0.f;
    constexpr int PF = 8;
    float buf[PF];
    #pragma unroll
    for (int i = 0; i < PF; ++i) buf[i] = act ? R[i * 10 + lane] : 0.f;

    for (int tb = 0; tb < T_STEPS; tb += PF) {
        #pragma unroll
        for (int i = 0; i < PF; ++i) {
            int t = tb + i;
            syn = fmaf(a, syn, buf[i]);
            mem = fmaf(b, mem, syn);
            if (act) memr_all[t * 10 + lane] = mem;
            int tn = t + PF;
            buf[i] = (act && tn < T_STEPS) ? R[tn * 10 + lane] : 0.f;
        }
    }
}

// ---------------------------------------------------------------- phase 2C
__global__ void k_mean(const float* __restrict__ memr_all, float* __restrict__ out) {
    int g = blockIdx.x * blockDim.x + threadIdx.x;
    if (g >= T_STEPS * 2) return;
    int t = g >> 1, o = g & 1;
    const float* m = memr_all + t * 10 + o;
    out[g] = 0.2f * (m[0] + m[2] + m[4] + m[6] + m[8]);
}

// ---------------------------------------------------------------- launch
extern "C" void kernel_launch(void* const* d_in, const int* in_sizes, int n_in,
                              void* d_out, int out_size, void* d_ws, size_t ws_size,
                              hipStream_t stream) {
    (void)in_sizes; (void)n_in; (void)out_size; (void)ws_size;
    const float* x       = (const float*)d_in[0];
    const float* W_in    = (const float*)d_in[1];
    const float* V       = (const float*)d_in[2];
    const float* b_rec   = (const float*)d_in[3];
    const float* W_out   = (const float*)d_in[4];
    const float* alpha_h = (const float*)d_in[5];
    const float* beta_h  = (const float*)d_in[6];
    const float* alpha_r = (const float*)d_in[7];
    const float* beta_r  = (const float*)d_in[8];
    float* out = (float*)d_out;

    unsigned int* spkWords = (unsigned int*)d_ws;                           // 2 MB
    float* R        = (float*)((char*)d_ws + (size_t)T_STEPS * 64 * 4);     // 320 KB
    float* memr_all = R + (size_t)T_STEPS * 10;                             // 320 KB

    int nclr = T_STEPS * 64;
    k_clear<<<(nclr + 255) / 256, 256, 0, stream>>>(spkWords, nclr);
    k_phase1<<<NBLK, 512, 0, stream>>>(x, W_in, V, b_rec, alpha_h, beta_h, spkWords);
    k_readout_mm<<<(T_STEPS + 24) / 25, 256, 0, stream>>>(spkWords, W_out, R);
    k_scan<<<1, 64, 0, stream>>>(R, alpha_r, beta_r, memr_all);
    k_mean<<<(T_STEPS * 2 + 255) / 256, 256, 0, stream>>>(memr_all, out);
}

// Round 3
// 30587.994 us; speedup vs baseline: 3.6966x; 3.6966x over previous
//
#include <hip/hip_runtime.h>
#include <hip/hip_bf16.h>

// bigRSNN: T=8192 strictly-serial spiking RNN.
// Phase 1: 64 blocks x 576 threads. Waves 0..7 compute 16 rows (2 per wave,
// 32 lanes per row, 32 V-columns per lane in VGPRs). Wave 8 = sync wave:
// while the compute waves work on step t (using step t-1 bits from LDS), it
// polls the 63 REMOTE tagged spike words for step t — remote latency hides
// under local compute. Publish: each compute wave's lane0 ds_adds its 2
// disjoint spike bits + (1<<16) into an LDS combiner; the wave seeing
// count==8 issues the single tagged agent-scope store (tag t+1 | bits16).
// One raw s_barrier per step, lgkmcnt-only (no vmcnt drain).
// Phase 2: readout GEMM over the raster + 10 IIR scans + head mean.

constexpr int T_STEPS = 8192;
constexpr int IN_DIM  = 192;
constexpr int H_DIM   = 1024;
constexpr int NBLK    = 64;

// ---------------------------------------------------------------- clear ws
__global__ void k_clear(unsigned int* __restrict__ p, int n) {
    int i = blockIdx.x * blockDim.x + threadIdx.x;
    if (i < n) p[i] = 0u;
}

// ---------------------------------------------------------------- phase 1
__global__ __launch_bounds__(576, 1) void k_phase1(
    const float* __restrict__ x,       // [T][192]
    const float* __restrict__ W_in,    // [H][192]
    const float* __restrict__ V,       // [H][H]
    const float* __restrict__ b_rec,   // [H]
    const float* __restrict__ alpha_h_p,
    const float* __restrict__ beta_h_p,
    unsigned int* __restrict__ spkWords) // [T][64] : (t+1)<<16 | bits16
{
    const int tid   = threadIdx.x;
    const int blk   = blockIdx.x;       // 0..63
    const int w     = tid >> 6;         // wave 0..8
    const int l     = tid & 63;
    const bool sync = (w == 8);
    const int half  = l >> 5;           // which of the wave's 2 rows
    const int cg    = l & 31;           // column group: cols cg*32..+31
    const int row   = (blk << 4) + (w << 1) + half;   // valid for compute waves

    __shared__ unsigned int bits_lds[2][64];   // payload-only (16-bit) words
    __shared__ unsigned int combine[2];        // bits 0..15 | count<<16

    if (tid < 64) { bits_lds[0][tid] = 0u; bits_lds[1][tid] = 0u; }
    if (tid == 0) { combine[0] = 0u; combine[1] = 0u; }

    // ---- compute-wave register state ----
    float4 vfrag[8];
    float  wfrag[6];
    float  b_r = 0.f;
    if (!sync) {
        const float4* vp = (const float4*)(V + (size_t)row * H_DIM + cg * 32);
        #pragma unroll
        for (int i = 0; i < 8; ++i) vfrag[i] = vp[i];
        const float* wp = W_in + row * IN_DIM + cg * 6;
        #pragma unroll
        for (int i = 0; i < 6; ++i) wfrag[i] = wp[i];
        b_r = b_rec[row];
    }
    const float ah = alpha_h_p[0];
    const float bh = beta_h_p[0];

    const float* xptr = x + cg * 6;
    float xr[6], xf[6];
    #pragma unroll
    for (int i = 0; i < 6; ++i) { xr[i] = 0.0f; xf[i] = 0.0f; }

    float syn = 0.f, mem = 0.f, prev = 0.f;   // replicated across a row's 32 lanes

    __syncthreads();

    for (int t = 0; t < T_STEPS; ++t) {
        const int rs = (t + 1) & 1;   // read slot: step t-1 bits (init zeros at t=0)
        const int wslot = t & 1;      // write slot: step t bits

        if (!sync) {
            // prefetch x[t] (consumed next iteration as x[(t+1)-1])
            #pragma unroll
            for (int i = 0; i < 6; ++i) xf[i] = xptr[i];

            unsigned int b0 = bits_lds[rs][cg * 2];
            unsigned int b1 = bits_lds[rs][cg * 2 + 1];

            // V @ S_{t-1} over my 32 columns (two parallel FMA chains)
            float a0 = 0.f, a1 = 0.f;
            #pragma unroll
            for (int i = 0; i < 4; ++i) {
                a0 = fmaf((float)((b0 >> (4 * i + 0)) & 1u), vfrag[i].x, a0);
                a0 = fmaf((float)((b0 >> (4 * i + 1)) & 1u), vfrag[i].y, a0);
                a0 = fmaf((float)((b0 >> (4 * i + 2)) & 1u), vfrag[i].z, a0);
                a0 = fmaf((float)((b0 >> (4 * i + 3)) & 1u), vfrag[i].w, a0);
                a1 = fmaf((float)((b1 >> (4 * i + 0)) & 1u), vfrag[4 + i].x, a1);
                a1 = fmaf((float)((b1 >> (4 * i + 1)) & 1u), vfrag[4 + i].y, a1);
                a1 = fmaf((float)((b1 >> (4 * i + 2)) & 1u), vfrag[4 + i].z, a1);
                a1 = fmaf((float)((b1 >> (4 * i + 3)) & 1u), vfrag[4 + i].w, a1);
            }
            // + W_in @ x[t-1]
            #pragma unroll
            for (int i = 0; i < 6; ++i) a1 = fmaf(wfrag[i], xr[i], a1);
            float acc = a0 + a1;

            // reduce across the row's 32 lanes (xor < 32 stays within half)
            #pragma unroll
            for (int m = 1; m < 32; m <<= 1) acc += __shfl_xor(acc, m, 64);

            // state update (identical across the row's lanes)
            float cur = acc + b_r;
            syn = fmaf(ah, syn, cur);
            mem = fmaf(bh, mem, syn) * (1.0f - prev);   // zero-reset, prev spike
            float spk = (mem > 1.0f) ? 1.0f : 0.0f;
            prev = spk;

            // publish: ballot -> lane0 ds_add; count==8 wave does the store
            unsigned long long bal = __ballot(spk > 0.5f);
            if (l == 0) {
                unsigned int add = ((unsigned int)(bal & 1ull)         << (2 * w))
                                 | ((unsigned int)((bal >> 32) & 1ull) << (2 * w + 1))
                                 | 0x10000u;
                unsigned int old = __hip_atomic_fetch_add(&combine[wslot], add,
                                      __ATOMIC_RELAXED, __HIP_MEMORY_SCOPE_WORKGROUP);
                unsigned int newv = old + add;
                if ((newv >> 16) == 8u) {
                    unsigned int bits = newv & 0xffffu;
                    __hip_atomic_store(&spkWords[(size_t)t * 64 + blk],
                                       ((unsigned int)(t + 1) << 16) | bits,
                                       __ATOMIC_RELAXED, __HIP_MEMORY_SCOPE_AGENT);
                    bits_lds[wslot][blk] = bits;   // own bits for next iter
                    combine[wslot] = 0u;           // re-arm for step t+2
                }
            }

            #pragma unroll
            for (int i = 0; i < 6; ++i) xr[i] = xf[i];
            xptr += IN_DIM;
        } else {
            // sync wave: poll step-t words of the 63 remote blocks
            if (t + 1 < T_STEPS) {
                const bool own = (l == blk);
                const unsigned int want = (unsigned int)(t + 1);
                const unsigned int* pw = &spkWords[(size_t)t * 64 + l];
                unsigned int nv = own ? (want << 16)
                                      : __hip_atomic_load(pw, __ATOMIC_RELAXED,
                                                          __HIP_MEMORY_SCOPE_AGENT);
                while (__any((nv >> 16) != want)) {
                    if ((nv >> 16) != want)
                        nv = __hip_atomic_load(pw, __ATOMIC_RELAXED,
                                               __HIP_MEMORY_SCOPE_AGENT);
                }
                if (!own) bits_lds[wslot][l] = nv & 0xffffu;
            }
        }

        asm volatile("s_waitcnt lgkmcnt(0)" ::: "memory");
        __builtin_amdgcn_s_barrier();
        __builtin_amdgcn_sched_barrier(0);
    }
}

// ---------------------------------------------------------------- phase 2A
// R[t][row] = W_out[row] . S_{t-1}  (row = h*2+o, 10 rows). W_out staged in
// LDS with pad (stride 1033) to break row-bank conflicts.
__global__ __launch_bounds__(256, 1) void k_readout_mm(
    const unsigned int* __restrict__ spkWords,
    const float* __restrict__ W_out,   // [10][1024]
    float* __restrict__ R)             // [T][10]
{
    __shared__ float wlds[10 * 1033];
    for (int i = threadIdx.x; i < 10 * 1024; i += 256) {
        int r = i >> 10, c = i & 1023;
        wlds[r * 1033 + c] = W_out[i];
    }
    __syncthreads();

    int tid = threadIdx.x;
    if (tid >= 250) return;
    int tl = tid / 10, rowr = tid - tl * 10;
    int t = blockIdx.x * 25 + tl;
    if (t >= T_STEPS) return;

    float acc = 0.f;
    if (t > 0) {
        const unsigned int* wp = spkWords + (size_t)(t - 1) * 64;
        const float* wr = &wlds[rowr * 1033];
        for (int ww = 0; ww < 64; ++ww) {
            unsigned int bits = wp[ww] & 0xffffu;
            const float* wb = wr + ww * 16;
            #pragma unroll
            for (int j = 0; j < 16; ++j)
                acc = fmaf((float)((bits >> j) & 1u), wb[j], acc);
        }
    }
    R[t * 10 + rowr] = acc;
}

// ---------------------------------------------------------------- phase 2B
__global__ void k_scan(const float* __restrict__ R,
                       const float* __restrict__ alpha_r,
                       const float* __restrict__ beta_r,
                       float* __restrict__ memr_all)   // [T][10]
{
    int lane = threadIdx.x;
    bool act = lane < 10;
    float a = act ? alpha_r[lane >> 1] : 0.f;
    float b = act ? beta_r[lane >> 1] : 0.f;
    float syn = 0.f, mem = 0.f;
    constexpr int PF = 8;
    float buf[PF];
    #pragma unroll
    for (int i = 0; i < PF; ++i) buf[i] = act ? R[i * 10 + lane] : 0.f;

    for (int tb = 0; tb < T_STEPS; tb += PF) {
        #pragma unroll
        for (int i = 0; i < PF; ++i) {
            int t = tb + i;
            syn = fmaf(a, syn, buf[i]);
            mem = fmaf(b, mem, syn);
            if (act) memr_all[t * 10 + lane] = mem;
            int tn = t + PF;
            buf[i] = (act && tn < T_STEPS) ? R[tn * 10 + lane] : 0.f;
        }
    }
}

// ---------------------------------------------------------------- phase 2C
__global__ void k_mean(const float* __restrict__ memr_all, float* __restrict__ out) {
    int g = blockIdx.x * blockDim.x + threadIdx.x;
    if (g >= T_STEPS * 2) return;
    int t = g >> 1, o = g & 1;
    const float* m = memr_all + t * 10 + o;
    out[g] = 0.2f * (m[0] + m[2] + m[4] + m[6] + m[8]);
}

// ---------------------------------------------------------------- launch
extern "C" void kernel_launch(void* const* d_in, const int* in_sizes, int n_in,
                              void* d_out, int out_size, void* d_ws, size_t ws_size,
                              hipStream_t stream) {
    (void)in_sizes; (void)n_in; (void)out_size; (void)ws_size;
    const float* x       = (const float*)d_in[0];
    const float* W_in    = (const float*)d_in[1];
    const float* V       = (const float*)d_in[2];
    const float* b_rec   = (const float*)d_in[3];
    const float* W_out   = (const float*)d_in[4];
    const float* alpha_h = (const float*)d_in[5];
    const float* beta_h  = (const float*)d_in[6];
    const float* alpha_r = (const float*)d_in[7];
    const float* beta_r  = (const float*)d_in[8];
    float* out = (float*)d_out;

    unsigned int* spkWords = (unsigned int*)d_ws;                           // 2 MB
    float* R        = (float*)((char*)d_ws + (size_t)T_STEPS * 64 * 4);     // 320 KB
    float* memr_all = R + (size_t)T_STEPS * 10;                             // 320 KB

    int nclr = T_STEPS * 64;
    k_clear<<<(nclr + 255) / 256, 256, 0, stream>>>(spkWords, nclr);
    k_phase1<<<NBLK, 576, 0, stream>>>(x, W_in, V, b_rec, alpha_h, beta_h, spkWords);
    k_readout_mm<<<(T_STEPS + 24) / 25, 256, 0, stream>>>(spkWords, W_out, R);
    k_scan<<<1, 64, 0, stream>>>(R, alpha_r, beta_r, memr_all);
    k_mean<<<(T_STEPS * 2 + 255) / 256, 256, 0, stream>>>(memr_all, out);
}

// Round 4
// 18472.800 us; speedup vs baseline: 6.1211x; 1.6558x over previous
//
#include <hip/hip_runtime.h>
#include <hip/hip_bf16.h>

// bigRSNN: T=8192 strictly-serial spiking RNN.
// Phase 1: 32 blocks x 576 threads. Waves 0..7 compute 32 rows (4 rows/wave,
// 16 lanes/row, 64 V-cols per lane in VGPRs). Wave 8 = sync wave: polls the
// 31 remote block flags for step t concurrently with the compute waves'
// step-t work. Flags: one u64 per (step ring slot, block), PADDED to a
// private 64-B sector; the u64 = two self-validating words, each
// (t+1)<<16 | bits16, published by ONE relaxed agent atomic store from the
// last-arriving wave (LDS u64 add combiner: low32 = spike bits, high32 =
// arrival count). One raw s_barrier per step (lgkm-only drain).
// Phase 2: readout GEMM over the tagged raster + 10 IIR scans + head mean.

constexpr int T_STEPS = 8192;
constexpr int IN_DIM  = 192;
constexpr int H_DIM   = 1024;
constexpr int NBLK    = 32;
constexpr int RING    = 4;    // flag ring slots (skew bound is 1; 4 is safe)

// ---------------------------------------------------------------- clear ws
__global__ void k_clear(unsigned int* __restrict__ p, int n) {
    int i = blockIdx.x * blockDim.x + threadIdx.x;
    if (i < n) p[i] = 0u;
}

// ---------------------------------------------------------------- phase 1
__global__ __launch_bounds__(576, 1) void k_phase1(
    const float* __restrict__ x,        // [T][192]
    const float* __restrict__ W_in,     // [H][192]
    const float* __restrict__ V,        // [H][H]
    const float* __restrict__ b_rec,    // [H]
    const float* __restrict__ alpha_h_p,
    const float* __restrict__ beta_h_p,
    unsigned long long* __restrict__ ringFlags, // [RING][32] u64, 64B stride
    uint2* __restrict__ raster)         // [T][32] tagged words
{
    const int tid   = threadIdx.x;
    const int blk   = blockIdx.x;        // 0..31
    const int w     = tid >> 6;          // wave 0..8
    const int l     = tid & 63;
    const bool syncw = (w == 8);
    const int r_local = l >> 4;          // 0..3 (row within wave)
    const int cg      = l & 15;          // column group: cols cg*64..+63
    const int row   = (blk << 5) + (w << 2) + r_local; // compute waves only

    __shared__ unsigned int       bits_lds[2][NBLK];  // 32 spike bits per block
    __shared__ unsigned long long combine[2];         // low32 bits | count<<32

    if (tid < NBLK) { bits_lds[0][tid] = 0u; bits_lds[1][tid] = 0u; }
    if (tid == 0)   { combine[0] = 0ull; combine[1] = 0ull; }

    // ---- compute-wave register state ----
    float4 vfrag[16];
    float  wfrag[12];
    float  b_r = 0.f;
    if (!syncw) {
        const float4* vp = (const float4*)(V + (size_t)row * H_DIM + cg * 64);
        #pragma unroll
        for (int i = 0; i < 16; ++i) vfrag[i] = vp[i];
        const float* wp = W_in + row * IN_DIM + cg * 12;
        #pragma unroll
        for (int i = 0; i < 12; ++i) wfrag[i] = wp[i];
        b_r = b_rec[row];
    }
    const float ah = alpha_h_p[0];
    const float bh = beta_h_p[0];

    const float* xptr = x + cg * 12;     // 12 floats per lane, 16B-aligned
    float xr[12];
    #pragma unroll
    for (int i = 0; i < 12; ++i) xr[i] = 0.0f;   // x[-1] = 0

    float syn = 0.f, mem = 0.f, prev = 0.f;  // replicated across a row's 16 lanes

    __syncthreads();

    for (int t = 0; t < T_STEPS; ++t) {
        const int rs = (t + 1) & 1;   // read slot: step t-1 bits
        const int wsl = t & 1;        // write slot: step t bits

        if (!syncw) {
            // prefetch x[t] (consumed next iteration)
            const float4* xp4 = (const float4*)xptr;
            float4 f0 = xp4[0], f1 = xp4[1], f2 = xp4[2];

            unsigned int b0 = bits_lds[rs][2 * cg];       // cols cg*64..+31
            unsigned int b1 = bits_lds[rs][2 * cg + 1];   // cols cg*64+32..+63

            // V @ S_{t-1} over my 64 columns (two parallel FMA chains)
            float a0 = 0.f, a1 = 0.f;
            #pragma unroll
            for (int i = 0; i < 8; ++i) {
                a0 = fmaf((float)((b0 >> (4 * i + 0)) & 1u), vfrag[i].x, a0);
                a0 = fmaf((float)((b0 >> (4 * i + 1)) & 1u), vfrag[i].y, a0);
                a0 = fmaf((float)((b0 >> (4 * i + 2)) & 1u), vfrag[i].z, a0);
                a0 = fmaf((float)((b0 >> (4 * i + 3)) & 1u), vfrag[i].w, a0);
                a1 = fmaf((float)((b1 >> (4 * i + 0)) & 1u), vfrag[8 + i].x, a1);
                a1 = fmaf((float)((b1 >> (4 * i + 1)) & 1u), vfrag[8 + i].y, a1);
                a1 = fmaf((float)((b1 >> (4 * i + 2)) & 1u), vfrag[8 + i].z, a1);
                a1 = fmaf((float)((b1 >> (4 * i + 3)) & 1u), vfrag[8 + i].w, a1);
            }
            // + W_in @ x[t-1] over my 12 k's
            #pragma unroll
            for (int i = 0; i < 12; ++i) a0 = fmaf(wfrag[i], xr[i], a0);
            float acc = a0 + a1;

            // reduce across the row's 16 lanes
            #pragma unroll
            for (int m = 1; m < 16; m <<= 1) acc += __shfl_xor(acc, m, 64);

            // state update (identical across the row's 16 lanes)
            float cur = acc + b_r;
            syn = fmaf(ah, syn, cur);
            mem = fmaf(bh, mem, syn) * (1.0f - prev);  // zero-reset, prev spike
            float spk = (mem > 1.0f) ? 1.0f : 0.0f;
            prev = spk;

            // publish: ballot -> lane0 packs 4-bit nibble -> LDS u64 combine
            unsigned long long bal = __ballot(spk > 0.5f);
            if (l == 0) {
                unsigned int nib = (unsigned int)(bal & 1ull)
                                 | ((unsigned int)((bal >> 16) & 1ull) << 1)
                                 | ((unsigned int)((bal >> 32) & 1ull) << 2)
                                 | ((unsigned int)((bal >> 48) & 1ull) << 3);
                unsigned long long add =
                    (1ull << 32) | ((unsigned long long)nib << (4 * w));
                unsigned long long old = __hip_atomic_fetch_add(&combine[wsl], add,
                        __ATOMIC_RELAXED, __HIP_MEMORY_SCOPE_WORKGROUP);
                unsigned long long nv = old + add;
                if ((nv >> 32) == 8ull) {                 // last wave: publish
                    unsigned int bits = (unsigned int)nv;
                    unsigned int want = (unsigned int)(t + 1);
                    unsigned int w0 = (want << 16) | (bits & 0xffffu);
                    unsigned int w1 = (want << 16) | (bits >> 16);
                    unsigned long long pack =
                        (unsigned long long)w0 | ((unsigned long long)w1 << 32);
                    __hip_atomic_store(
                        &ringFlags[(size_t)(((t & (RING - 1)) << 5) | blk) << 3],
                        pack, __ATOMIC_RELAXED, __HIP_MEMORY_SCOPE_AGENT);
                    raster[(size_t)t * NBLK + blk] = make_uint2(w0, w1);
                    bits_lds[wsl][blk] = bits;            // own bits for t+1
                    combine[wsl] = 0ull;                  // re-arm for t+2
                }
            }

            #pragma unroll
            for (int i = 0; i < 4; ++i) {
                xr[i]     = (&f0.x)[i];
                xr[4 + i] = (&f1.x)[i];
                xr[8 + i] = (&f2.x)[i];
            }
            xptr += IN_DIM;
        } else {
            // sync wave: poll step-t flags of the 31 remote blocks
            if (t + 1 < T_STEPS) {
                const bool act = (l < NBLK) && (l != blk);
                const unsigned int want = (unsigned int)(t + 1);
                const unsigned long long good =
                    ((unsigned long long)want << 16) |
                    ((unsigned long long)want << 48);
                const unsigned long long* p =
                    &ringFlags[(size_t)(((t & (RING - 1)) << 5) | l) << 3];
                unsigned long long vv = act
                    ? __hip_atomic_load(p, __ATOMIC_RELAXED, __HIP_MEMORY_SCOPE_AGENT)
                    : good;
                bool ok = (((vv >> 16) & 0xffffull) == want) && ((vv >> 48) == want);
                while (__any(!ok)) {
                    if (!ok) {
                        vv = __hip_atomic_load(p, __ATOMIC_RELAXED,
                                               __HIP_MEMORY_SCOPE_AGENT);
                        ok = (((vv >> 16) & 0xffffull) == want) && ((vv >> 48) == want);
                    }
                }
                if (act)
                    bits_lds[wsl][l] = (unsigned int)(vv & 0xffffull)
                                     | ((unsigned int)((vv >> 32) & 0xffffull) << 16);
            }
        }

        asm volatile("s_waitcnt lgkmcnt(0)" ::: "memory");
        __builtin_amdgcn_s_barrier();
        __builtin_amdgcn_sched_barrier(0);
    }
}

// ---------------------------------------------------------------- phase 2A
// R[t][rr] = W_out[rr] . S_{t-1}  (rr = h*2+o, 10 rows). W_out staged in LDS
// with pad (stride 1033) to break row-bank conflicts.
__global__ __launch_bounds__(256, 1) void k_readout_mm(
    const uint2* __restrict__ raster,  // [T][32] tagged words
    const float* __restrict__ W_out,   // [10][1024]
    float* __restrict__ R)             // [T][10]
{
    __shared__ float wlds[10 * 1033];
    for (int i = threadIdx.x; i < 10 * 1024; i += 256) {
        int r = i >> 10, c = i & 1023;
        wlds[r * 1033 + c] = W_out[i];
    }
    __syncthreads();

    int tid = threadIdx.x;
    if (tid >= 250) return;
    int tl = tid / 10, rowr = tid - tl * 10;
    int t = blockIdx.x * 25 + tl;
    if (t >= T_STEPS) return;

    float acc = 0.f;
    if (t > 0) {
        const uint2* wp = raster + (size_t)(t - 1) * NBLK;
        const float* wr = &wlds[rowr * 1033];
        for (int ww = 0; ww < NBLK; ++ww) {
            uint2 v = wp[ww];
            unsigned int bits = (v.x & 0xffffu) | ((v.y & 0xffffu) << 16);
            const float* wb = wr + ww * 32;
            #pragma unroll
            for (int j = 0; j < 32; ++j)
                acc = fmaf((float)((bits >> j) & 1u), wb[j], acc);
        }
    }
    R[t * 10 + rowr] = acc;
}

// ---------------------------------------------------------------- phase 2B
__global__ void k_scan(const float* __restrict__ R,
                       const float* __restrict__ alpha_r,
                       const float* __restrict__ beta_r,
                       float* __restrict__ memr_all)   // [T][10]
{
    int lane = threadIdx.x;
    bool act = lane < 10;
    float a = act ? alpha_r[lane >> 1] : 0.f;
    float b = act ? beta_r[lane >> 1] : 0.f;
    float syn = 0.f, mem = 0.f;
    constexpr int PF = 8;
    float buf[PF];
    #pragma unroll
    for (int i = 0; i < PF; ++i) buf[i] = act ? R[i * 10 + lane] : 0.f;

    for (int tb = 0; tb < T_STEPS; tb += PF) {
        #pragma unroll
        for (int i = 0; i < PF; ++i) {
            int t = tb + i;
            syn = fmaf(a, syn, buf[i]);
            mem = fmaf(b, mem, syn);
            if (act) memr_all[t * 10 + lane] = mem;
            int tn = t + PF;
            buf[i] = (act && tn < T_STEPS) ? R[tn * 10 + lane] : 0.f;
        }
    }
}

// ---------------------------------------------------------------- phase 2C
__global__ void k_mean(const float* __restrict__ memr_all, float* __restrict__ out) {
    int g = blockIdx.x * blockDim.x + threadIdx.x;
    if (g >= T_STEPS * 2) return;
    int t = g >> 1, o = g & 1;
    const float* m = memr_all + t * 10 + o;
    out[g] = 0.2f * (m[0] + m[2] + m[4] + m[6] + m[8]);
}

// ---------------------------------------------------------------- launch
extern "C" void kernel_launch(void* const* d_in, const int* in_sizes, int n_in,
                              void* d_out, int out_size, void* d_ws, size_t ws_size,
                              hipStream_t stream) {
    (void)in_sizes; (void)n_in; (void)out_size; (void)ws_size;
    const float* x       = (const float*)d_in[0];
    const float* W_in    = (const float*)d_in[1];
    const float* V       = (const float*)d_in[2];
    const float* b_rec   = (const float*)d_in[3];
    const float* W_out   = (const float*)d_in[4];
    const float* alpha_h = (const float*)d_in[5];
    const float* beta_h  = (const float*)d_in[6];
    const float* alpha_r = (const float*)d_in[7];
    const float* beta_r  = (const float*)d_in[8];
    float* out = (float*)d_out;

    char* wsb = (char*)d_ws;
    unsigned long long* ringFlags = (unsigned long long*)wsb;      // 8 KB
    uint2* raster  = (uint2*)(wsb + RING * NBLK * 64);             // 2 MB
    float* Rbuf    = (float*)(wsb + RING * NBLK * 64
                              + (size_t)T_STEPS * NBLK * 8);       // 320 KB
    float* memr_all = Rbuf + (size_t)T_STEPS * 10;                 // 320 KB

    int nclr = RING * NBLK * 16;   // ring region in u32s (64B per entry)
    k_clear<<<(nclr + 255) / 256, 256, 0, stream>>>((unsigned int*)ringFlags, nclr);
    k_phase1<<<NBLK, 576, 0, stream>>>(x, W_in, V, b_rec, alpha_h, beta_h,
                                       ringFlags, raster);
    k_readout_mm<<<(T_STEPS + 24) / 25, 256, 0, stream>>>(raster, W_out, Rbuf);
    k_scan<<<1, 64, 0, stream>>>(Rbuf, alpha_r, beta_r, memr_all);
    k_mean<<<(T_STEPS * 2 + 255) / 256, 256, 0, stream>>>(memr_all, out);
}